// Round 1
// baseline (349.184 us; speedup 1.0000x reference)
//
#include <hip/hip_runtime.h>
#include <hip/hip_bf16.h>
#include <cstdint>

typedef __bf16 bf16x8 __attribute__((ext_vector_type(8)));
typedef __bf16 bf16x4 __attribute__((ext_vector_type(4)));
typedef float f32x4 __attribute__((ext_vector_type(4)));

#define SLEN 4096
#define DMODEL 1280
#define NHEADS 16
#define HD 80
#define HDP 96

// ---------------- fp32 -> bf16 elementwise (float4 loads) ----------------
__global__ __launch_bounds__(256) void cvt_f32_bf16(const float* __restrict__ in,
                                                    __bf16* __restrict__ out, int n4) {
  int i = blockIdx.x * 256 + threadIdx.x;
  if (i < n4) {
    float4 v = ((const float4*)in)[i];
    bf16x4 o = { (__bf16)v.x, (__bf16)v.y, (__bf16)v.z, (__bf16)v.w };
    ((bf16x4*)out)[i] = o;
  }
}

// ------------- transpose + cvt: in (K,N) f32 -> out (N,K) bf16 -----------
__global__ __launch_bounds__(256) void transpose_cvt(const float* __restrict__ in,
                                                     __bf16* __restrict__ out,
                                                     int K, int N) {
  __shared__ float tile[32][33];
  int n0 = blockIdx.x * 32, k0 = blockIdx.y * 32;
  int x = threadIdx.x & 31, y = threadIdx.x >> 5;  // y in 0..7
  for (int i = 0; i < 32; i += 8)
    tile[y + i][x] = in[(size_t)(k0 + y + i) * N + n0 + x];
  __syncthreads();
  for (int i = 0; i < 32; i += 8)
    out[(size_t)(n0 + y + i) * K + k0 + x] = (__bf16)tile[x][y + i];
}

// ------ GEMM: C(M,N) = A(M,K)[row-major] * Bt(N,K)[row-major]^T + bias ------
// 128x128 block tile, 4 waves in 2x2 grid, each wave 64x64 (4x4 MFMA 16x16x32).
// LDS stride 40 elems (80 B): 16B-aligned b128 reads, 2-way bank alias (free).
__global__ __launch_bounds__(256) void gemm_bt(const __bf16* __restrict__ A,
                                               const __bf16* __restrict__ Bt,
                                               const float* __restrict__ bias,
                                               void* __restrict__ C,
                                               int M, int N, int K, int store_bf16) {
  __shared__ __attribute__((aligned(16))) __bf16 As[128][40];
  __shared__ __attribute__((aligned(16))) __bf16 Bs[128][40];
  const int t = threadIdx.x;
  const int lane = t & 63, wave = t >> 6;
  const int quad = lane >> 4, l15 = lane & 15;
  const int wm = (wave & 1) * 64, wn = (wave >> 1) * 64;
  const int bm = blockIdx.x * 128, bn = blockIdx.y * 128;

  const int row = t >> 1;          // 0..127
  const int colc = (t & 1) * 16;   // 0 or 16 (element offset in 32-wide K-tile)
  const __bf16* Ag = A + (size_t)(bm + row) * K + colc;
  const __bf16* Bg = Bt + (size_t)(bn + row) * K + colc;

  f32x4 acc[4][4] = {};

  for (int k0 = 0; k0 < K; k0 += 32) {
    uint4 a0 = *(const uint4*)(Ag + k0);
    uint4 a1 = *(const uint4*)(Ag + k0 + 8);
    uint4 b0 = *(const uint4*)(Bg + k0);
    uint4 b1 = *(const uint4*)(Bg + k0 + 8);
    __syncthreads();
    *(uint4*)&As[row][colc] = a0;
    *(uint4*)&As[row][colc + 8] = a1;
    *(uint4*)&Bs[row][colc] = b0;
    *(uint4*)&Bs[row][colc + 8] = b1;
    __syncthreads();
    bf16x8 af[4], bfr[4];
    for (int i = 0; i < 4; ++i)
      af[i] = *(const bf16x8*)&As[wm + i * 16 + l15][quad * 8];
    for (int j = 0; j < 4; ++j)
      bfr[j] = *(const bf16x8*)&Bs[wn + j * 16 + l15][quad * 8];
    for (int i = 0; i < 4; ++i)
      for (int j = 0; j < 4; ++j)
        acc[i][j] = __builtin_amdgcn_mfma_f32_16x16x32_bf16(af[i], bfr[j], acc[i][j], 0, 0, 0);
  }

  // C layout (m89-verified): col = lane&15, row = quad*4 + reg
  for (int j = 0; j < 4; ++j) {
    int col = bn + wn + j * 16 + l15;
    float bv = bias[col];
    for (int i = 0; i < 4; ++i) {
      int r0 = bm + wm + i * 16 + quad * 4;
      for (int r = 0; r < 4; ++r) {
        float v = acc[i][j][r] + bv;
        if (store_bf16)
          ((__bf16*)C)[(size_t)(r0 + r) * N + col] = (__bf16)v;
        else
          ((float*)C)[(size_t)(r0 + r) * N + col] = v;
      }
    }
  }
}

// --- RoPE q,k -> (H,S,96) padded bf16 (q pre-scaled by log2e/sqrt(80)); ---
// --- V transposed to (H, 80, S) bf16 via LDS tile.                      ---
__global__ __launch_bounds__(256) void rope_pack(const __bf16* __restrict__ qkv,
                                                 const float* __restrict__ freqs,
                                                 __bf16* __restrict__ qp,
                                                 __bf16* __restrict__ kp,
                                                 __bf16* __restrict__ vt) {
  const float QSCALE = 0.11180339887498949f * 1.44269504088896340f; // 1/sqrt(80) * log2(e)
  int h = blockIdx.y;
  int s0 = blockIdx.x * 64;
  __shared__ float vtile[64][81];

  for (int idx = threadIdx.x; idx < 64 * 96; idx += 256) {
    int sp = idx / 96, d = idx % 96;
    int s = s0 + sp;
    float oq = 0.f, ok = 0.f;
    if (d < 80) {
      int dd = (d < 40) ? d : d - 40;
      float f = freqs[s * 40 + dd];
      float cs = cosf(f), sn = sinf(f);
      const __bf16* base = qkv + (size_t)s * 3840 + h * 80;
      float x1 = (float)base[dd], x2 = (float)base[dd + 40];
      float y1 = (float)base[1280 + dd], y2 = (float)base[1280 + dd + 40];
      if (d < 40) { oq = x1 * cs - x2 * sn; ok = y1 * cs - y2 * sn; }
      else        { oq = x1 * sn + x2 * cs; ok = y1 * sn + y2 * cs; }
      oq *= QSCALE;
    }
    size_t o = (size_t)(h * SLEN + s) * HDP + d;
    qp[o] = (__bf16)oq;
    kp[o] = (__bf16)ok;
  }

  for (int idx = threadIdx.x; idx < 64 * 80; idx += 256) {
    int sp = idx / 80, d = idx % 80;
    vtile[sp][d] = (float)qkv[(size_t)(s0 + sp) * 3840 + 2560 + h * 80 + d];
  }
  __syncthreads();
  for (int idx = threadIdx.x; idx < 80 * 64; idx += 256) {
    int d = idx >> 6, sp = idx & 63;
    vt[(size_t)(h * 80 + d) * SLEN + s0 + sp] = (__bf16)vtile[sp][d];
  }
}

// ----------------- flash attention over block-diagonal segments -----------------
// Block = (64 q-rows, head); 4 waves, each wave owns 16 q-rows, iterates 32-key tiles.
__global__ __launch_bounds__(256) void flash_attn(const __bf16* __restrict__ qp,
                                                  const __bf16* __restrict__ kp,
                                                  const __bf16* __restrict__ vt,
                                                  const int* __restrict__ cu, int nseg,
                                                  __bf16* __restrict__ out) {
  int h = blockIdx.y;
  int q0 = blockIdx.x * 64;
  int seg = 0;
  for (int i = 1; i < nseg; ++i)
    if (cu[i] <= q0) seg = i;
  int kstart = cu[seg], kend = cu[seg + 1];

  int t = threadIdx.x;
  int lane = t & 63, wave = t >> 6;
  int quad = lane >> 4, l15 = lane & 15;

  __shared__ __attribute__((aligned(16))) __bf16 Ks[32][104];   // keys x d (pad 96->104)
  __shared__ __attribute__((aligned(16))) __bf16 Vs[80][40];    // d x keys (pad 32->40)
  __shared__ __attribute__((aligned(16))) __bf16 Ps[4][16][40]; // per-wave P tile

  bf16x8 qf[3];
  {
    const __bf16* qptr = qp + (size_t)(h * SLEN + q0 + wave * 16 + l15) * HDP + quad * 8;
    qf[0] = *(const bf16x8*)(qptr);
    qf[1] = *(const bf16x8*)(qptr + 32);
    qf[2] = *(const bf16x8*)(qptr + 64);
  }

  f32x4 o[5] = {};
  float m_i[4], l_i[4];
  for (int r = 0; r < 4; ++r) { m_i[r] = -1e30f; l_i[r] = 0.f; }

  for (int kc = kstart; kc < kend; kc += 32) {
    __syncthreads();
    for (int idx = t; idx < 384; idx += 256) {   // K tile: 32 rows x 12 chunks of 16B
      int key = idx / 12, c = idx % 12;
      *(uint4*)&Ks[key][c * 8] = *(const uint4*)&kp[(size_t)(h * SLEN + kc + key) * HDP + c * 8];
    }
    for (int idx = t; idx < 320; idx += 256) {   // V tile: 80 rows x 4 chunks of 16B
      int d = idx >> 2, c = idx & 3;
      *(uint4*)&Vs[d][c * 8] = *(const uint4*)&vt[(size_t)(h * 80 + d) * SLEN + kc + c * 8];
    }
    __syncthreads();

    // S = Q K^T (scores already in log2 units, scaled via Q)
    f32x4 sc[2] = {};
    for (int n = 0; n < 2; ++n)
      for (int c = 0; c < 3; ++c) {
        bf16x8 kf = *(const bf16x8*)&Ks[n * 16 + l15][quad * 8 + c * 32];
        sc[n] = __builtin_amdgcn_mfma_f32_16x16x32_bf16(qf[c], kf, sc[n], 0, 0, 0);
      }

    // online softmax: stats replicated across the 16 lanes of each quad
    float mnew[4], alpha[4], rs[4];
    for (int r = 0; r < 4; ++r) {
      float mx = fmaxf(sc[0][r], sc[1][r]);
      for (int off = 1; off < 16; off <<= 1)
        mx = fmaxf(mx, __shfl_xor(mx, off));
      mnew[r] = fmaxf(m_i[r], mx);
      alpha[r] = __builtin_amdgcn_exp2f(m_i[r] - mnew[r]);
      m_i[r] = mnew[r];
      rs[r] = 0.f;
    }

    __bf16 pb[2][4];
    for (int n = 0; n < 2; ++n)
      for (int r = 0; r < 4; ++r) {
        float p = __builtin_amdgcn_exp2f(sc[n][r] - mnew[r]);
        rs[r] += p;
        pb[n][r] = (__bf16)p;
      }
    for (int r = 0; r < 4; ++r) {
      for (int off = 1; off < 16; off <<= 1)
        rs[r] += __shfl_xor(rs[r], off);
      l_i[r] = l_i[r] * alpha[r] + rs[r];
    }
    for (int nt = 0; nt < 5; ++nt)
      for (int r = 0; r < 4; ++r)
        o[nt][r] *= alpha[r];

    // P: C-layout -> LDS -> A-layout (m120 pattern), per-wave private region
    for (int n = 0; n < 2; ++n)
      for (int r = 0; r < 4; ++r)
        Ps[wave][quad * 4 + r][n * 16 + l15] = pb[n][r];

    bf16x8 pf = *(const bf16x8*)&Ps[wave][l15][quad * 8];
    for (int nt = 0; nt < 5; ++nt) {
      bf16x8 vf = *(const bf16x8*)&Vs[nt * 16 + l15][quad * 8];
      o[nt] = __builtin_amdgcn_mfma_f32_16x16x32_bf16(pf, vf, o[nt], 0, 0, 0);
    }
  }

  for (int nt = 0; nt < 5; ++nt)
    for (int r = 0; r < 4; ++r) {
      int rowi = q0 + wave * 16 + quad * 4 + r;
      int col = h * 80 + nt * 16 + l15;
      out[(size_t)rowi * DMODEL + col] = (__bf16)(o[nt][r] / l_i[r]);
    }
}

extern "C" void kernel_launch(void* const* d_in, const int* in_sizes, int n_in,
                              void* d_out, int out_size, void* d_ws, size_t ws_size,
                              hipStream_t stream) {
  const float* hidden = (const float*)d_in[0];
  const int* cu       = (const int*)d_in[1];
  const float* freqs  = (const float*)d_in[2];
  const float* w_qkv  = (const float*)d_in[3];
  const float* b_qkv  = (const float*)d_in[4];
  const float* w_proj = (const float*)d_in[5];
  const float* b_proj = (const float*)d_in[6];
  float* out = (float*)d_out;

  char* ws = (char*)d_ws;
  size_t off = 0;
  auto alloc = [&](size_t bytes) {
    char* p = ws + off;
    off += (bytes + 255) & ~(size_t)255;
    return p;
  };
  __bf16* hid_b  = (__bf16*)alloc((size_t)SLEN * DMODEL * 2);
  __bf16* wqkvT  = (__bf16*)alloc((size_t)3840 * 1280 * 2);
  __bf16* wprojT = (__bf16*)alloc((size_t)1280 * 1280 * 2);
  __bf16* qkvb   = (__bf16*)alloc((size_t)SLEN * 3840 * 2);
  __bf16* qp     = (__bf16*)alloc((size_t)NHEADS * SLEN * HDP * 2);
  __bf16* kp     = (__bf16*)alloc((size_t)NHEADS * SLEN * HDP * 2);
  __bf16* vt     = (__bf16*)alloc((size_t)NHEADS * HD * SLEN * 2);
  __bf16* attn   = hid_b;  // alias: hid_b dead after qkv GEMM, attn written after

  cvt_f32_bf16<<<(SLEN * DMODEL / 4 + 255) / 256, 256, 0, stream>>>(hidden, hid_b, SLEN * DMODEL / 4);
  transpose_cvt<<<dim3(3840 / 32, 1280 / 32), 256, 0, stream>>>(w_qkv, wqkvT, 1280, 3840);
  transpose_cvt<<<dim3(1280 / 32, 1280 / 32), 256, 0, stream>>>(w_proj, wprojT, 1280, 1280);
  gemm_bt<<<dim3(SLEN / 128, 3840 / 128), 256, 0, stream>>>(hid_b, wqkvT, b_qkv, qkvb,
                                                            SLEN, 3840, 1280, 1);
  rope_pack<<<dim3(SLEN / 64, NHEADS), 256, 0, stream>>>(qkvb, freqs, qp, kp, vt);
  int nseg = in_sizes[1] - 1;
  flash_attn<<<dim3(SLEN / 64, NHEADS), 256, 0, stream>>>(qp, kp, vt, cu, nseg, attn);
  gemm_bt<<<dim3(SLEN / 128, DMODEL / 128), 256, 0, stream>>>(attn, wprojT, b_proj, out,
                                                              SLEN, DMODEL, 1280, 0);
}